// Round 11
// baseline (118.430 us; speedup 1.0000x reference)
//
#include <hip/hip_runtime.h>
#include <hip/hip_bf16.h>
#include <math.h>

#define FEAT 384
#define FFN  768
#define ZDIM 384
#define HID  192
#define BB   4
#define NN   128
#define BN   (BB*NN)   // 512 rows

__device__ __forceinline__ float gelu_exact(float x) {
    return 0.5f * x * (1.0f + erff(x * 0.70710678118654752440f));
}

__device__ __forceinline__ float bflo(unsigned u) { return __uint_as_float(u << 16); }
__device__ __forceinline__ float bfhi(unsigned u) { return __uint_as_float(u & 0xFFFF0000u); }

template<bool F32>
__device__ __forceinline__ float ldg(const void* p, int i) {
    if constexpr (F32) return ((const float*)p)[i];
    return __uint_as_float(((unsigned)((const unsigned short*)p)[i]) << 16);
}
template<bool F32>
__device__ __forceinline__ void stg(void* p, size_t i, float v) {
    if constexpr (F32) ((float*)p)[i] = v;
    else ((__hip_bfloat16*)p)[i] = __float2bfloat16(v);
}

template<bool F32> struct V8;
template<> struct V8<true> {
    float4 a, b;
    __device__ __forceinline__ void load(const void* p, size_t off) {
        a = *(const float4*)((const float*)p + off);
        b = *(const float4*)((const float*)p + off + 4);
    }
    __device__ __forceinline__ float g(int i) const {
        return (i < 4) ? (&a.x)[i] : (&b.x)[i - 4];
    }
};
template<> struct V8<false> {
    uint4 u;
    __device__ __forceinline__ void load(const void* p, size_t off) {
        u = *(const uint4*)((const unsigned short*)p + off);
    }
    __device__ __forceinline__ float g(int i) const {
        const unsigned w = (&u.x)[i >> 1];
        return (i & 1) ? bfhi(w) : bflo(w);
    }
};
template<bool F32> struct V4;
template<> struct V4<true> {
    float4 a;
    __device__ __forceinline__ void load(const void* p, size_t off) {
        a = *(const float4*)((const float*)p + off);
    }
    __device__ __forceinline__ float g(int i) const { return (&a.x)[i]; }
};
template<> struct V4<false> {
    uint2 u;
    __device__ __forceinline__ void load(const void* p, size_t off) {
        u = *(const uint2*)((const unsigned short*)p + off);
    }
    __device__ __forceinline__ float g(int i) const {
        const unsigned w = (&u.x)[i >> 1];
        return (i & 1) ? bfhi(w) : bflo(w);
    }
};

__device__ __forceinline__ bool is_f32(const void* ln_w) {
    return ((const unsigned short*)ln_w)[0] == 0;
}

// ---- block reductions over 384 threads (6 wave64); sm holds 12 floats ----
__device__ __forceinline__ float block_sum(float v, float* sm) {
    for (int o = 32; o > 0; o >>= 1) v += __shfl_down(v, o, 64);
    const int lane = threadIdx.x & 63, w = threadIdx.x >> 6;
    __syncthreads();
    if (lane == 0) sm[w] = v;
    __syncthreads();
    return sm[0] + sm[1] + sm[2] + sm[3] + sm[4] + sm[5];
}
__device__ __forceinline__ float2 block_sum2(float vx, float vy, float* sm) {
    for (int o = 32; o > 0; o >>= 1) {
        vx += __shfl_down(vx, o, 64);
        vy += __shfl_down(vy, o, 64);
    }
    const int lane = threadIdx.x & 63, w = threadIdx.x >> 6;
    __syncthreads();
    if (lane == 0) { sm[w] = vx; sm[w + 6] = vy; }
    __syncthreads();
    return make_float2(sm[0] + sm[1] + sm[2] + sm[3] + sm[4] + sm[5],
                       sm[6] + sm[7] + sm[8] + sm[9] + sm[10] + sm[11]);
}
__device__ __forceinline__ float block_max(float v, float* sm) {
    for (int o = 32; o > 0; o >>= 1) v = fmaxf(v, __shfl_down(v, o, 64));
    const int lane = threadIdx.x & 63, w = threadIdx.x >> 6;
    __syncthreads();
    if (lane == 0) sm[w] = v;
    __syncthreads();
    return fmaxf(fmaxf(fmaxf(sm[0], sm[1]), fmaxf(sm[2], sm[3])), fmaxf(sm[4], sm[5]));
}

// Shared-pool layout (floats): xs0 0, xs1 384, zs0 768, zs1 1152,
// hid0 1536, hid1 1728, gh 1920, part 2112 (5376), sm 7488. Total 7500.
#define SM_TOTAL 7500

// ============ Type A: pair p — U z-half -> LN -> enc -> dec -> dots ============
template<bool F32>
__device__ void bodyA(float* S, int pr,
    const void* __restrict__ x, const void* __restrict__ U_w,
    const void* __restrict__ U_b, const void* __restrict__ ln_w,
    const void* __restrict__ ln_b, const void* __restrict__ enc_w,
    const void* __restrict__ enc_b, const void* __restrict__ dec_w,
    const void* __restrict__ dec_b,
    float* __restrict__ d0, float* __restrict__ diag)
{
    const int r0 = 2 * pr, r1 = r0 + 1;
    const int t = threadIdx.x;
    float* xs0 = S;        float* xs1 = S + 384;
    float* zs0 = S + 768;  float* zs1 = S + 1152;
    float* hid0 = S + 1536; float* hid1 = S + 1728;
    float* gh = S + 1920;
    float* part = S + 2112;
    float* sm = S + 7488;

    xs0[t] = ldg<F32>(x, r0 * FEAT + t);
    xs1[t] = ldg<F32>(x, r1 * FEAT + t);
    if (t < HID) gh[t] = gelu_exact(ldg<F32>(enc_b, t));
    __syncthreads();

    // U z-half: cg=t%48 -> cols 8cg..+7 (global 384+), kh=t/48 -> K 48kh..+48
    const int cg = t % 48, kh = t / 48;
    const int cL = 8 * cg, cG = ZDIM + cL, kb = 48 * kh;
    float a0[8] = {0,0,0,0,0,0,0,0}, a1[8] = {0,0,0,0,0,0,0,0};
    {
        V8<F32> wa[8], wb[8];
        #pragma unroll
        for (int j = 0; j < 8; j++) wa[j].load(U_w, (size_t)(kb + j) * FFN + cG);
        for (int k0 = kb; k0 < kb + 48; k0 += 16) {
            #pragma unroll
            for (int j = 0; j < 8; j++) wb[j].load(U_w, (size_t)(k0 + 8 + j) * FFN + cG);
            #pragma unroll
            for (int j = 0; j < 8; j++) {
                const float x0 = xs0[k0 + j], x1 = xs1[k0 + j];
                #pragma unroll
                for (int i = 0; i < 8; i++) {
                    const float w = wa[j].g(i);
                    a0[i] = fmaf(x0, w, a0[i]);
                    a1[i] = fmaf(x1, w, a1[i]);
                }
            }
            if (k0 + 16 < kb + 48) {
                #pragma unroll
                for (int j = 0; j < 8; j++) wa[j].load(U_w, (size_t)(k0 + 16 + j) * FFN + cG);
            }
            #pragma unroll
            for (int j = 0; j < 8; j++) {
                const float x0 = xs0[k0 + 8 + j], x1 = xs1[k0 + 8 + j];
                #pragma unroll
                for (int i = 0; i < 8; i++) {
                    const float w = wb[j].g(i);
                    a0[i] = fmaf(x0, w, a0[i]);
                    a1[i] = fmaf(x1, w, a1[i]);
                }
            }
        }
    }
    if (kh > 0) {
        float* p = &part[(kh - 1) * 768 + cg];
        #pragma unroll
        for (int i = 0; i < 8; i++) { p[i * 48] = a0[i]; p[384 + i * 48] = a1[i]; }
    }
    __syncthreads();

    float h0[8], h1[8];
    float s1a = 0.f, s1b = 0.f, s2a = 0.f, s2b = 0.f;
    if (kh == 0) {
        #pragma unroll
        for (int i = 0; i < 8; i++) {
            const float ub = ldg<F32>(U_b, cG + i);
            float v0 = a0[i] + ub, v1 = a1[i] + ub;
            #pragma unroll
            for (int kk = 0; kk < 7; kk++) {
                v0 += part[kk * 768 + i * 48 + cg];
                v1 += part[kk * 768 + 384 + i * 48 + cg];
            }
            v0 = gelu_exact(v0); v1 = gelu_exact(v1);
            h0[i] = v0; h1[i] = v1;
            s1a += v0; s2a += v0 * v0;
            s1b += v1; s2b += v1 * v1;
        }
    }
    const float2 S1 = block_sum2(s1a, s1b, sm);
    const float2 S2 = block_sum2(s2a, s2b, sm);
    const float mu0 = S1.x * (1.0f / ZDIM), mu1 = S1.y * (1.0f / ZDIM);
    const float rs0 = rsqrtf(S2.x * (1.0f / ZDIM) - mu0 * mu0 + 1e-5f);
    const float rs1 = rsqrtf(S2.y * (1.0f / ZDIM) - mu1 * mu1 + 1e-5f);
    if (kh == 0) {
        #pragma unroll
        for (int i = 0; i < 8; i++) {
            const int zc = cL + i;
            const float w = ldg<F32>(ln_w, zc), bb = ldg<F32>(ln_b, zc);
            zs0[zc] = (h0[i] - mu0) * rs0 * w + bb;
            zs1[zc] = (h1[i] - mu1) * rs1 * w + bb;
        }
    }
    __syncthreads();

    // encoder: cgE=t%48 -> 4 cols of 192; khE=t/48 -> K 48khE..+48
    {
        const int cgE = t % 48, khE = t / 48;
        const int cE = 4 * cgE, kbE = 48 * khE;
        float e0a[4] = {0,0,0,0}, e1a[4] = {0,0,0,0};
        V4<F32> va[8], vb[8];
        #pragma unroll
        for (int j = 0; j < 8; j++) va[j].load(enc_w, (size_t)(kbE + j) * HID + cE);
        for (int k0 = kbE; k0 < kbE + 48; k0 += 16) {
            #pragma unroll
            for (int j = 0; j < 8; j++) vb[j].load(enc_w, (size_t)(k0 + 8 + j) * HID + cE);
            #pragma unroll
            for (int j = 0; j < 8; j++) {
                const float z0 = zs0[k0 + j], z1 = zs1[k0 + j];
                #pragma unroll
                for (int i = 0; i < 4; i++) {
                    const float w = va[j].g(i);
                    e0a[i] = fmaf(z0, w, e0a[i]);
                    e1a[i] = fmaf(z1, w, e1a[i]);
                }
            }
            if (k0 + 16 < kbE + 48) {
                #pragma unroll
                for (int j = 0; j < 8; j++) va[j].load(enc_w, (size_t)(k0 + 16 + j) * HID + cE);
            }
            #pragma unroll
            for (int j = 0; j < 8; j++) {
                const float z0 = zs0[k0 + 8 + j], z1 = zs1[k0 + 8 + j];
                #pragma unroll
                for (int i = 0; i < 4; i++) {
                    const float w = vb[j].g(i);
                    e0a[i] = fmaf(z0, w, e0a[i]);
                    e1a[i] = fmaf(z1, w, e1a[i]);
                }
            }
        }
        if (khE > 0) {
            float* p = &part[(khE - 1) * 384 + cgE];
            #pragma unroll
            for (int i = 0; i < 4; i++) { p[i * 48] = e0a[i]; p[192 + i * 48] = e1a[i]; }
        }
        __syncthreads();
        if (khE == 0) {
            #pragma unroll
            for (int i = 0; i < 4; i++) {
                const float ebv = ldg<F32>(enc_b, cE + i);
                float v0 = e0a[i] + ebv, v1 = e1a[i] + ebv;
                #pragma unroll
                for (int kk = 0; kk < 7; kk++) {
                    v0 += part[kk * 384 + i * 48 + cgE];
                    v1 += part[kk * 384 + 192 + i * 48 + cgE];
                }
                hid0[cE + i] = gelu_exact(v0);
                hid1[cE + i] = gelu_exact(v1);
            }
        }
        __syncthreads();
    }

    // decoder: cgD=t%96 -> 4 cols of 384; khD=t/96 -> K 48khD..+48
    {
        const int cgD = t % 96, khD = t / 96;
        const int cD = 4 * cgD, kbD = 48 * khD;
        float aa[4] = {0,0,0,0}, ab_[4] = {0,0,0,0}, ac[4] = {0,0,0,0};
        V4<F32> va[8], vb[8];
        #pragma unroll
        for (int j = 0; j < 8; j++) va[j].load(dec_w, (size_t)(kbD + j) * ZDIM + cD);
        for (int k0 = kbD; k0 < kbD + 48; k0 += 16) {
            #pragma unroll
            for (int j = 0; j < 8; j++) vb[j].load(dec_w, (size_t)(k0 + 8 + j) * ZDIM + cD);
            #pragma unroll
            for (int j = 0; j < 8; j++) {
                const float v0 = hid0[k0 + j], v1 = hid1[k0 + j], gv = gh[k0 + j];
                #pragma unroll
                for (int i = 0; i < 4; i++) {
                    const float w = va[j].g(i);
                    aa[i] = fmaf(v0, w, aa[i]);
                    ab_[i] = fmaf(v1, w, ab_[i]);
                    ac[i] = fmaf(gv, w, ac[i]);
                }
            }
            if (k0 + 16 < kbD + 48) {
                #pragma unroll
                for (int j = 0; j < 8; j++) va[j].load(dec_w, (size_t)(k0 + 16 + j) * ZDIM + cD);
            }
            #pragma unroll
            for (int j = 0; j < 8; j++) {
                const float v0 = hid0[k0 + 8 + j], v1 = hid1[k0 + 8 + j], gv = gh[k0 + 8 + j];
                #pragma unroll
                for (int i = 0; i < 4; i++) {
                    const float w = vb[j].g(i);
                    aa[i] = fmaf(v0, w, aa[i]);
                    ab_[i] = fmaf(v1, w, ab_[i]);
                    ac[i] = fmaf(gv, w, ac[i]);
                }
            }
        }
        if (khD > 0) {
            float* p = &part[(khD - 1) * 1152 + cgD];
            #pragma unroll
            for (int i = 0; i < 4; i++) {
                p[i * 96] = aa[i]; p[384 + i * 96] = ab_[i]; p[768 + i * 96] = ac[i];
            }
        }
        __syncthreads();
        float pd0 = 0.f, pd1 = 0.f, pe0 = 0.f, pe1 = 0.f;
        if (khD == 0) {
            #pragma unroll
            for (int i = 0; i < 4; i++) {
                const int c = cD + i;
                const float dbv = ldg<F32>(dec_b, c);
                float v0 = aa[i] + dbv, v1 = ab_[i] + dbv, v2 = ac[i] + dbv;
                #pragma unroll
                for (int kk = 0; kk < 3; kk++) {
                    v0 += part[kk * 1152 + i * 96 + cgD];
                    v1 += part[kk * 1152 + 384 + i * 96 + cgD];
                    v2 += part[kk * 1152 + 768 + i * 96 + cgD];
                }
                const float z0 = zs0[c], z1 = zs1[c];
                pd0 = fmaf(v0, z0, pd0);
                pd1 = fmaf(v1, z1, pd1);
                pe0 = fmaf(v2, z0, pe0);
                pe1 = fmaf(v2, z1, pe1);
            }
        }
        const float2 DG = block_sum2(pd0, pd1, sm);
        const float2 DD = block_sum2(pe0, pe1, sm);
        if (t == 0) {
            diag[r0] = DG.x; diag[r1] = DG.y;
            d0[r0] = DD.x;   d0[r1] = DD.y;
        }
    }
}

// ============ Type B: pair p — U xh-half -> Y = xh @ V_w ============
template<bool F32>
__device__ void bodyB(float* S, int pr,
    const void* __restrict__ x, const void* __restrict__ U_w,
    const void* __restrict__ U_b, const void* __restrict__ V_w,
    float* __restrict__ Y)
{
    const int r0 = 2 * pr, r1 = r0 + 1;
    const int t = threadIdx.x;
    float* xs0 = S;        float* xs1 = S + 384;
    float* zs0 = S + 768;  float* zs1 = S + 1152;
    float* part = S + 2112;

    xs0[t] = ldg<F32>(x, r0 * FEAT + t);
    xs1[t] = ldg<F32>(x, r1 * FEAT + t);
    __syncthreads();

    const int cg = t % 48, kh = t / 48;
    const int cL = 8 * cg, kb = 48 * kh;
    float a0[8] = {0,0,0,0,0,0,0,0}, a1[8] = {0,0,0,0,0,0,0,0};
    {
        V8<F32> wa[8], wb[8];
        #pragma unroll
        for (int j = 0; j < 8; j++) wa[j].load(U_w, (size_t)(kb + j) * FFN + cL);
        for (int k0 = kb; k0 < kb + 48; k0 += 16) {
            #pragma unroll
            for (int j = 0; j < 8; j++) wb[j].load(U_w, (size_t)(k0 + 8 + j) * FFN + cL);
            #pragma unroll
            for (int j = 0; j < 8; j++) {
                const float x0 = xs0[k0 + j], x1 = xs1[k0 + j];
                #pragma unroll
                for (int i = 0; i < 8; i++) {
                    const float w = wa[j].g(i);
                    a0[i] = fmaf(x0, w, a0[i]);
                    a1[i] = fmaf(x1, w, a1[i]);
                }
            }
            if (k0 + 16 < kb + 48) {
                #pragma unroll
                for (int j = 0; j < 8; j++) wa[j].load(U_w, (size_t)(k0 + 16 + j) * FFN + cL);
            }
            #pragma unroll
            for (int j = 0; j < 8; j++) {
                const float x0 = xs0[k0 + 8 + j], x1 = xs1[k0 + 8 + j];
                #pragma unroll
                for (int i = 0; i < 8; i++) {
                    const float w = wb[j].g(i);
                    a0[i] = fmaf(x0, w, a0[i]);
                    a1[i] = fmaf(x1, w, a1[i]);
                }
            }
        }
    }
    if (kh > 0) {
        float* p = &part[(kh - 1) * 768 + cg];
        #pragma unroll
        for (int i = 0; i < 8; i++) { p[i * 48] = a0[i]; p[384 + i * 48] = a1[i]; }
    }
    __syncthreads();
    if (kh == 0) {
        #pragma unroll
        for (int i = 0; i < 8; i++) {
            const float ub = ldg<F32>(U_b, cL + i);
            float v0 = a0[i] + ub, v1 = a1[i] + ub;
            #pragma unroll
            for (int kk = 0; kk < 7; kk++) {
                v0 += part[kk * 768 + i * 48 + cg];
                v1 += part[kk * 768 + 384 + i * 48 + cg];
            }
            zs0[cL + i] = gelu_exact(v0);
            zs1[cL + i] = gelu_exact(v1);
        }
    }
    __syncthreads();

    // V: same mapping; Y[r, cL..cL+7]
    float y0[8] = {0,0,0,0,0,0,0,0}, y1[8] = {0,0,0,0,0,0,0,0};
    {
        V8<F32> va[8], vb[8];
        #pragma unroll
        for (int j = 0; j < 8; j++) va[j].load(V_w, (size_t)(kb + j) * FEAT + cL);
        for (int k0 = kb; k0 < kb + 48; k0 += 16) {
            #pragma unroll
            for (int j = 0; j < 8; j++) vb[j].load(V_w, (size_t)(k0 + 8 + j) * FEAT + cL);
            #pragma unroll
            for (int j = 0; j < 8; j++) {
                const float s0 = zs0[k0 + j], s1 = zs1[k0 + j];
                #pragma unroll
                for (int i = 0; i < 8; i++) {
                    const float w = va[j].g(i);
                    y0[i] = fmaf(s0, w, y0[i]);
                    y1[i] = fmaf(s1, w, y1[i]);
                }
            }
            if (k0 + 16 < kb + 48) {
                #pragma unroll
                for (int j = 0; j < 8; j++) va[j].load(V_w, (size_t)(k0 + 16 + j) * FEAT + cL);
            }
            #pragma unroll
            for (int j = 0; j < 8; j++) {
                const float s0 = zs0[k0 + 8 + j], s1 = zs1[k0 + 8 + j];
                #pragma unroll
                for (int i = 0; i < 8; i++) {
                    const float w = vb[j].g(i);
                    y0[i] = fmaf(s0, w, y0[i]);
                    y1[i] = fmaf(s1, w, y1[i]);
                }
            }
        }
    }
    if (kh > 0) {
        float* p = &part[(kh - 1) * 768 + cg];
        #pragma unroll
        for (int i = 0; i < 8; i++) { p[i * 48] = y0[i]; p[384 + i * 48] = y1[i]; }
    }
    __syncthreads();
    if (kh == 0) {
        float o0[8], o1[8];
        #pragma unroll
        for (int i = 0; i < 8; i++) {
            float u0 = y0[i], u1 = y1[i];
            #pragma unroll
            for (int kk = 0; kk < 7; kk++) {
                u0 += part[kk * 768 + i * 48 + cg];
                u1 += part[kk * 768 + 384 + i * 48 + cg];
            }
            o0[i] = u0; o1[i] = u1;
        }
        *(float4*)(Y + (size_t)r0 * FEAT + cL)     = make_float4(o0[0], o0[1], o0[2], o0[3]);
        *(float4*)(Y + (size_t)r0 * FEAT + cL + 4) = make_float4(o0[4], o0[5], o0[6], o0[7]);
        *(float4*)(Y + (size_t)r1 * FEAT + cL)     = make_float4(o1[0], o1[1], o1[2], o1[3]);
        *(float4*)(Y + (size_t)r1 * FEAT + cL + 4) = make_float4(o1[4], o1[5], o1[6], o1[7]);
    }
}

__global__ __launch_bounds__(384) void k_main(
    const void* x, const void* U_w, const void* U_b,
    const void* ln_w, const void* ln_b,
    const void* enc_w, const void* enc_b,
    const void* dec_w, const void* dec_b, const void* V_w,
    float* Y, float* d0, float* diag)
{
    __shared__ float S[SM_TOTAL];   // single pool shared by all template paths
    const int type = blockIdx.x & 1;
    const int pr = blockIdx.x >> 1;
    if (is_f32(ln_w)) {
        if (type == 0) bodyA<true >(S, pr, x, U_w, U_b, ln_w, ln_b, enc_w, enc_b, dec_w, dec_b, d0, diag);
        else           bodyB<true >(S, pr, x, U_w, U_b, V_w, Y);
    } else {
        if (type == 0) bodyA<false>(S, pr, x, U_w, U_b, ln_w, ln_b, enc_w, enc_b, dec_w, dec_b, d0, diag);
        else           bodyB<false>(S, pr, x, U_w, U_b, V_w, Y);
    }
}

// ============ K2: 16 blocks = 4 batches x 4 col-chunks of 96 ============
template<bool F32>
__device__ void combine_body(
    const float* __restrict__ d0, const float* __restrict__ diag,
    const float* __restrict__ Y,
    const void* __restrict__ V_b, void* __restrict__ out)
{
    const int b  = blockIdx.x >> 2;
    const int cc = (blockIdx.x & 3) * 96;
    const int t = threadIdx.x;
    const int c = t % 96, q = t / 96;
    __shared__ float e0s[NN], eds[NN];
    __shared__ float bp[4 * 96];
    __shared__ float baseY[96];
    __shared__ float sm[12];

    float d0v = -INFINITY, dgv = -INFINITY;
    if (t < NN) { d0v = d0[b * NN + t]; dgv = diag[b * NN + t]; }
    const float m = block_max(fmaxf(d0v, dgv), sm);
    float e0v = 0.f;
    if (t < NN) {
        e0v = expf(d0v - m);
        e0s[t] = e0v;
        eds[t] = expf(dgv - m);
    }
    const float S = block_sum(e0v, sm);

    const float* Yb = Y + (size_t)b * NN * FEAT + cc + c;
    const int j0 = 32 * q;
    float p = 0.f;
    for (int jj = 0; jj < 32; jj += 8) {
        float w[8];
        #pragma unroll
        for (int j = 0; j < 8; j++) w[j] = Yb[(size_t)(j0 + jj + j) * FEAT];
        #pragma unroll
        for (int j = 0; j < 8; j++) p = fmaf(e0s[j0 + jj + j], w[j], p);
    }
    bp[q * 96 + c] = p;
    __syncthreads();
    if (q == 0) baseY[c] = bp[c] + bp[96 + c] + bp[192 + c] + bp[288 + c];
    __syncthreads();

    const float bY = baseY[c];
    const float vb = ldg<F32>(V_b, cc + c);
    for (int rr = 0; rr < 32; rr += 8) {
        float w[8];
        #pragma unroll
        for (int j = 0; j < 8; j++) w[j] = Yb[(size_t)(j0 + rr + j) * FEAT];
        #pragma unroll
        for (int j = 0; j < 8; j++) {
            const int r = j0 + rr + j;
            const float inv = 1.0f / (S - e0s[r] + eds[r]);
            const float val = (bY + (eds[r] - e0s[r]) * w[j]) * inv + vb;
            stg<F32>(out, (size_t)(b * NN + r) * FEAT + cc + c, val);
        }
    }
}

__global__ __launch_bounds__(384) void k_combine(
    const void* ln_w,
    const float* d0, const float* diag, const float* Y,
    const void* V_b, void* out)
{
    if (is_f32(ln_w))
        combine_body<true >(d0, diag, Y, V_b, out);
    else
        combine_body<false>(d0, diag, Y, V_b, out);
}

extern "C" void kernel_launch(void* const* d_in, const int* in_sizes, int n_in,
                              void* d_out, int out_size, void* d_ws, size_t ws_size,
                              hipStream_t stream) {
    const void* x     = d_in[0];
    const void* U_w   = d_in[1];
    const void* U_b   = d_in[2];
    const void* ln_w  = d_in[3];
    const void* ln_b  = d_in[4];
    const void* enc_w = d_in[5];
    const void* enc_b = d_in[6];
    const void* dec_w = d_in[7];
    const void* dec_b = d_in[8];
    const void* V_w   = d_in[9];
    const void* V_b   = d_in[10];

    float* ws   = (float*)d_ws;
    float* Y    = ws;                     // 512*384  (xh @ V_w, no bias)
    float* d0   = Y + (size_t)BN * FEAT;  // 512
    float* diag = d0 + BN;                // 512

    k_main<<<BN, 384, 0, stream>>>(x, U_w, U_b, ln_w, ln_b, enc_w, enc_b,
                                   dec_w, dec_b, V_w, Y, d0, diag);
    k_combine<<<4 * BB, 384, 0, stream>>>(ln_w, d0, diag, Y, V_b, d_out);
}

// Round 12
// 103.817 us; speedup vs baseline: 1.1408x; 1.1408x over previous
//
#include <hip/hip_runtime.h>
#include <hip/hip_bf16.h>
#include <math.h>

#define FEAT 384
#define FFN  768
#define ZDIM 384
#define HID  192
#define BB   4
#define NN   128
#define BN   (BB*NN)   // 512 rows

__device__ __forceinline__ float gelu_exact(float x) {
    return 0.5f * x * (1.0f + erff(x * 0.70710678118654752440f));
}

__device__ __forceinline__ float bflo(unsigned u) { return __uint_as_float(u << 16); }
__device__ __forceinline__ float bfhi(unsigned u) { return __uint_as_float(u & 0xFFFF0000u); }

template<bool F32>
__device__ __forceinline__ float ldg(const void* p, int i) {
    if constexpr (F32) return ((const float*)p)[i];
    return __uint_as_float(((unsigned)((const unsigned short*)p)[i]) << 16);
}
template<bool F32>
__device__ __forceinline__ void stg(void* p, size_t i, float v) {
    if constexpr (F32) ((float*)p)[i] = v;
    else ((__hip_bfloat16*)p)[i] = __float2bfloat16(v);
}

// 4-element weight vector: 16B load (fp32) / 8B load (bf16)
template<bool F32> struct V4;
template<> struct V4<true> {
    float4 a;
    __device__ __forceinline__ void load(const void* p, size_t off) {
        a = *(const float4*)((const float*)p + off);
    }
    __device__ __forceinline__ float g(int i) const { return (&a.x)[i]; }
};
template<> struct V4<false> {
    uint2 u;
    __device__ __forceinline__ void load(const void* p, size_t off) {
        u = *(const uint2*)((const unsigned short*)p + off);
    }
    __device__ __forceinline__ float g(int i) const {
        const unsigned w = (&u.x)[i >> 1];
        return (i & 1) ? bfhi(w) : bflo(w);
    }
};

__device__ __forceinline__ bool is_f32(const void* ln_w) {
    return ((const unsigned short*)ln_w)[0] == 0;
}

// ---- block reductions over 384 threads (6 wave64) ----
__device__ __forceinline__ float block_sum(float v, float* sm) {
    for (int o = 32; o > 0; o >>= 1) v += __shfl_down(v, o, 64);
    const int lane = threadIdx.x & 63, w = threadIdx.x >> 6;
    __syncthreads();
    if (lane == 0) sm[w] = v;
    __syncthreads();
    return sm[0] + sm[1] + sm[2] + sm[3] + sm[4] + sm[5];
}
__device__ __forceinline__ float block_max(float v, float* sm) {
    for (int o = 32; o > 0; o >>= 1) v = fmaxf(v, __shfl_down(v, o, 64));
    const int lane = threadIdx.x & 63, w = threadIdx.x >> 6;
    __syncthreads();
    if (lane == 0) sm[w] = v;
    __syncthreads();
    return fmaxf(fmaxf(fmaxf(sm[0], sm[1]), fmaxf(sm[2], sm[3])), fmaxf(sm[4], sm[5]));
}
// 4-wide block sum; sm must hold 24 floats
__device__ __forceinline__ void block_sum4(float v0, float v1, float v2, float v3,
                                           float* sm, float out[4]) {
    for (int o = 32; o > 0; o >>= 1) {
        v0 += __shfl_down(v0, o, 64);
        v1 += __shfl_down(v1, o, 64);
        v2 += __shfl_down(v2, o, 64);
        v3 += __shfl_down(v3, o, 64);
    }
    const int lane = threadIdx.x & 63, w = threadIdx.x >> 6;
    __syncthreads();
    if (lane == 0) { sm[w] = v0; sm[6 + w] = v1; sm[12 + w] = v2; sm[18 + w] = v3; }
    __syncthreads();
    #pragma unroll
    for (int q = 0; q < 4; q++)
        out[q] = sm[q*6] + sm[q*6+1] + sm[q*6+2] + sm[q*6+3] + sm[q*6+4] + sm[q*6+5];
}

// Shared pool (floats): xs 0 (1536), zs 1536 (1536), hid 3072 (768),
// gh 3840 (192), part 4032 (5760), sm 9792 (24). Total 9816 = 39.3 KB.
#define SM_TOTAL 9816

// Generic M=4 GEMM helper: 4 cols/thread (V4 loads), accum 4 rows x 4 cols,
// inputs from LDS rows in[m*ldin + k], weights W[k*ldw + c0].
template<bool F32, int KCH>
__device__ __forceinline__ void gemm4x4(
    const void* __restrict__ W, int ldw, int c0, int kb,
    const float* __restrict__ in, int ldin, float acc[4][4])
{
    V4<F32> wa[8], wb[8];
    #pragma unroll
    for (int j = 0; j < 8; j++) wa[j].load(W, (size_t)(kb + j) * ldw + c0);
    for (int k0 = kb; k0 < kb + KCH; k0 += 16) {
        #pragma unroll
        for (int j = 0; j < 8; j++) wb[j].load(W, (size_t)(k0 + 8 + j) * ldw + c0);
        #pragma unroll
        for (int j = 0; j < 8; j++) {
            #pragma unroll
            for (int m = 0; m < 4; m++) {
                const float xv = in[m * ldin + k0 + j];
                #pragma unroll
                for (int i = 0; i < 4; i++) acc[m][i] = fmaf(xv, wa[j].g(i), acc[m][i]);
            }
        }
        if (k0 + 16 < kb + KCH) {
            #pragma unroll
            for (int j = 0; j < 8; j++) wa[j].load(W, (size_t)(k0 + 16 + j) * ldw + c0);
        }
        #pragma unroll
        for (int j = 0; j < 8; j++) {
            #pragma unroll
            for (int m = 0; m < 4; m++) {
                const float xv = in[m * ldin + k0 + 8 + j];
                #pragma unroll
                for (int i = 0; i < 4; i++) acc[m][i] = fmaf(xv, wb[j].g(i), acc[m][i]);
            }
        }
    }
}

// ============ Type A: quad q — U z-half -> LN -> enc -> dec -> dots ============
template<bool F32>
__device__ void bodyA(float* S, int q,
    const void* __restrict__ x, const void* __restrict__ U_w,
    const void* __restrict__ U_b, const void* __restrict__ ln_w,
    const void* __restrict__ ln_b, const void* __restrict__ enc_w,
    const void* __restrict__ enc_b, const void* __restrict__ dec_w,
    const void* __restrict__ dec_b,
    float* __restrict__ d0, float* __restrict__ diag)
{
    const int rb = 4 * q;
    const int t = threadIdx.x;
    float* xs = S;          // 4 x 384
    float* zs = S + 1536;   // 4 x 384
    float* hid = S + 3072;  // 4 x 192
    float* gh = S + 3840;   // 192
    float* part = S + 4032; // up to 5760
    float* sm = S + 9792;   // 24

    #pragma unroll
    for (int m = 0; m < 4; m++) xs[m * 384 + t] = ldg<F32>(x, (rb + m) * FEAT + t);
    if (t < HID) gh[t] = gelu_exact(ldg<F32>(enc_b, t));
    __syncthreads();

    // ---- U z-half: cg=t%96 -> 4 cols (global 384+4cg); kh=t/96 -> K 96kh..+96 ----
    const int cg = t % 96, kh = t / 96;
    const int cL = 4 * cg, cG = ZDIM + cL, kb = 96 * kh;
    float acc[4][4] = {};
    gemm4x4<F32, 96>(U_w, FFN, cG, kb, xs, 384, acc);
    if (kh > 0) {
        float* p = &part[(kh - 1) * 1536 + cg];
        #pragma unroll
        for (int m = 0; m < 4; m++)
            #pragma unroll
            for (int i = 0; i < 4; i++) p[(m * 4 + i) * 96] = acc[m][i];
    }
    __syncthreads();

    float hv[4][4];
    float s1[4] = {0,0,0,0}, s2[4] = {0,0,0,0};
    if (kh == 0) {
        #pragma unroll
        for (int i = 0; i < 4; i++) {
            const float ub = ldg<F32>(U_b, cG + i);
            #pragma unroll
            for (int m = 0; m < 4; m++) {
                float v = acc[m][i] + ub
                        + part[(m * 4 + i) * 96 + cg]
                        + part[1536 + (m * 4 + i) * 96 + cg]
                        + part[3072 + (m * 4 + i) * 96 + cg];
                v = gelu_exact(v);
                hv[m][i] = v;
                s1[m] += v; s2[m] += v * v;
            }
        }
    }
    float S1[4], S2[4];
    block_sum4(s1[0], s1[1], s1[2], s1[3], sm, S1);
    block_sum4(s2[0], s2[1], s2[2], s2[3], sm, S2);
    if (kh == 0) {
        #pragma unroll
        for (int m = 0; m < 4; m++) {
            const float mu = S1[m] * (1.0f / ZDIM);
            const float rs = rsqrtf(S2[m] * (1.0f / ZDIM) - mu * mu + 1e-5f);
            #pragma unroll
            for (int i = 0; i < 4; i++) {
                const int zc = cL + i;
                zs[m * 384 + zc] = (hv[m][i] - mu) * rs * ldg<F32>(ln_w, zc) + ldg<F32>(ln_b, zc);
            }
        }
    }
    __syncthreads();

    // ---- encoder: cgE=t%48 -> 4 cols of 192; khE=t/48 -> K 48khE..+48 ----
    {
        const int cgE = t % 48, khE = t / 48;
        const int cE = 4 * cgE, kbE = 48 * khE;
        float ea[4][4] = {};
        gemm4x4<F32, 48>(enc_w, HID, cE, kbE, zs, 384, ea);
        if (khE > 0) {
            float* p = &part[(khE - 1) * 768 + cgE];
            #pragma unroll
            for (int m = 0; m < 4; m++)
                #pragma unroll
                for (int i = 0; i < 4; i++) p[(m * 4 + i) * 48] = ea[m][i];
        }
        __syncthreads();
        if (khE == 0) {
            #pragma unroll
            for (int i = 0; i < 4; i++) {
                const float ebv = ldg<F32>(enc_b, cE + i);
                #pragma unroll
                for (int m = 0; m < 4; m++) {
                    float v = ea[m][i] + ebv;
                    #pragma unroll
                    for (int kk = 0; kk < 7; kk++)
                        v += part[kk * 768 + (m * 4 + i) * 48 + cgE];
                    hid[m * 192 + cE + i] = gelu_exact(v);
                }
            }
        }
        __syncthreads();
    }

    // ---- decoder: cgD=t%96 -> 4 cols of 384; khD=t/96 -> K 48khD..+48 (K=192) ----
    {
        const int cgD = t % 96, khD = t / 96;
        const int cD = 4 * cgD, kbD = 48 * khD;
        float da[4][4] = {};
        float dc[4] = {0,0,0,0};    // AE(0) row
        {
            V4<F32> wa[8], wb[8];
            #pragma unroll
            for (int j = 0; j < 8; j++) wa[j].load(dec_w, (size_t)(kbD + j) * ZDIM + cD);
            for (int k0 = kbD; k0 < kbD + 48; k0 += 16) {
                #pragma unroll
                for (int j = 0; j < 8; j++) wb[j].load(dec_w, (size_t)(k0 + 8 + j) * ZDIM + cD);
                #pragma unroll
                for (int j = 0; j < 8; j++) {
                    const float gv = gh[k0 + j];
                    #pragma unroll
                    for (int i = 0; i < 4; i++) {
                        const float w = wa[j].g(i);
                        dc[i] = fmaf(gv, w, dc[i]);
                        #pragma unroll
                        for (int m = 0; m < 4; m++)
                            da[m][i] = fmaf(hid[m * 192 + k0 + j], w, da[m][i]);
                    }
                }
                if (k0 + 16 < kbD + 48) {
                    #pragma unroll
                    for (int j = 0; j < 8; j++) wa[j].load(dec_w, (size_t)(k0 + 16 + j) * ZDIM + cD);
                }
                #pragma unroll
                for (int j = 0; j < 8; j++) {
                    const float gv = gh[k0 + 8 + j];
                    #pragma unroll
                    for (int i = 0; i < 4; i++) {
                        const float w = wb[j].g(i);
                        dc[i] = fmaf(gv, w, dc[i]);
                        #pragma unroll
                        for (int m = 0; m < 4; m++)
                            da[m][i] = fmaf(hid[m * 192 + k0 + 8 + j], w, da[m][i]);
                    }
                }
            }
        }
        if (khD > 0) {
            float* p = &part[(khD - 1) * 1920 + cgD];
            #pragma unroll
            for (int m = 0; m < 4; m++)
                #pragma unroll
                for (int i = 0; i < 4; i++) p[(m * 4 + i) * 96] = da[m][i];
            #pragma unroll
            for (int i = 0; i < 4; i++) p[(16 + i) * 96] = dc[i];
        }
        __syncthreads();
        float pd[4] = {0,0,0,0}, pe[4] = {0,0,0,0};
        if (khD == 0) {
            #pragma unroll
            for (int i = 0; i < 4; i++) {
                const int c = cD + i;
                const float dbv = ldg<F32>(dec_b, c);
                float vc = dc[i] + dbv;
                #pragma unroll
                for (int kk = 0; kk < 3; kk++)
                    vc += part[kk * 1920 + (16 + i) * 96 + cgD];
                #pragma unroll
                for (int m = 0; m < 4; m++) {
                    float v = da[m][i] + dbv;
                    #pragma unroll
                    for (int kk = 0; kk < 3; kk++)
                        v += part[kk * 1920 + (m * 4 + i) * 96 + cgD];
                    const float zv = zs[m * 384 + c];
                    pd[m] = fmaf(v, zv, pd[m]);
                    pe[m] = fmaf(vc, zv, pe[m]);
                }
            }
        }
        float DG[4], DD[4];
        block_sum4(pd[0], pd[1], pd[2], pd[3], sm, DG);
        block_sum4(pe[0], pe[1], pe[2], pe[3], sm, DD);
        if (t == 0) {
            #pragma unroll
            for (int m = 0; m < 4; m++) { diag[rb + m] = DG[m]; d0[rb + m] = DD[m]; }
        }
    }
}

// ============ Type B: quad q — U xh-half -> Y = xh @ V_w ============
template<bool F32>
__device__ void bodyB(float* S, int q,
    const void* __restrict__ x, const void* __restrict__ U_w,
    const void* __restrict__ U_b, const void* __restrict__ V_w,
    float* __restrict__ Y)
{
    const int rb = 4 * q;
    const int t = threadIdx.x;
    float* xs = S;          // 4 x 384
    float* zs = S + 1536;   // 4 x 384 (xh)
    float* part = S + 4032;

    #pragma unroll
    for (int m = 0; m < 4; m++) xs[m * 384 + t] = ldg<F32>(x, (rb + m) * FEAT + t);
    __syncthreads();

    const int cg = t % 96, kh = t / 96;
    const int cL = 4 * cg, kb = 96 * kh;
    float acc[4][4] = {};
    gemm4x4<F32, 96>(U_w, FFN, cL, kb, xs, 384, acc);
    if (kh > 0) {
        float* p = &part[(kh - 1) * 1536 + cg];
        #pragma unroll
        for (int m = 0; m < 4; m++)
            #pragma unroll
            for (int i = 0; i < 4; i++) p[(m * 4 + i) * 96] = acc[m][i];
    }
    __syncthreads();
    if (kh == 0) {
        #pragma unroll
        for (int i = 0; i < 4; i++) {
            const float ub = ldg<F32>(U_b, cL + i);
            #pragma unroll
            for (int m = 0; m < 4; m++) {
                float v = acc[m][i] + ub
                        + part[(m * 4 + i) * 96 + cg]
                        + part[1536 + (m * 4 + i) * 96 + cg]
                        + part[3072 + (m * 4 + i) * 96 + cg];
                zs[m * 384 + cL + i] = gelu_exact(v);
            }
        }
    }
    __syncthreads();

    // V: same thread mapping; K = 384 full
    float ya[4][4] = {};
    gemm4x4<F32, 96>(V_w, FEAT, cL, kb, zs, 384, ya);
    if (kh > 0) {
        float* p = &part[(kh - 1) * 1536 + cg];
        #pragma unroll
        for (int m = 0; m < 4; m++)
            #pragma unroll
            for (int i = 0; i < 4; i++) p[(m * 4 + i) * 96] = ya[m][i];
    }
    __syncthreads();
    if (kh == 0) {
        #pragma unroll
        for (int m = 0; m < 4; m++) {
            float o[4];
            #pragma unroll
            for (int i = 0; i < 4; i++) {
                o[i] = ya[m][i]
                     + part[(m * 4 + i) * 96 + cg]
                     + part[1536 + (m * 4 + i) * 96 + cg]
                     + part[3072 + (m * 4 + i) * 96 + cg];
            }
            *(float4*)(Y + (size_t)(rb + m) * FEAT + cL) = make_float4(o[0], o[1], o[2], o[3]);
        }
    }
}

__global__ __launch_bounds__(384) void k_main(
    const void* x, const void* U_w, const void* U_b,
    const void* ln_w, const void* ln_b,
    const void* enc_w, const void* enc_b,
    const void* dec_w, const void* dec_b, const void* V_w,
    float* Y, float* d0, float* diag)
{
    __shared__ float S[SM_TOTAL];   // single pool for all template paths
    const int type = blockIdx.x & 1;
    const int q = blockIdx.x >> 1;
    if (is_f32(ln_w)) {
        if (type == 0) bodyA<true >(S, q, x, U_w, U_b, ln_w, ln_b, enc_w, enc_b, dec_w, dec_b, d0, diag);
        else           bodyB<true >(S, q, x, U_w, U_b, V_w, Y);
    } else {
        if (type == 0) bodyA<false>(S, q, x, U_w, U_b, ln_w, ln_b, enc_w, enc_b, dec_w, dec_b, d0, diag);
        else           bodyB<false>(S, q, x, U_w, U_b, V_w, Y);
    }
}

// ============ K2: 16 blocks = 4 batches x 4 col-chunks of 96 ============
// out_i = (baseY + (ed_i - e0_i) * Y_i) / (S - e0_i + ed_i) + V_b
template<bool F32>
__device__ void combine_body(
    const float* __restrict__ d0, const float* __restrict__ diag,
    const float* __restrict__ Y,
    const void* __restrict__ V_b, void* __restrict__ out)
{
    const int b  = blockIdx.x >> 2;
    const int cc = (blockIdx.x & 3) * 96;
    const int t = threadIdx.x;
    const int c = t % 96, qq = t / 96;
    __shared__ float e0s[NN], eds[NN];
    __shared__ float bp[4 * 96];
    __shared__ float baseY[96];
    __shared__ float sm[12];

    float d0v = -INFINITY, dgv = -INFINITY;
    if (t < NN) { d0v = d0[b * NN + t]; dgv = diag[b * NN + t]; }
    const float m = block_max(fmaxf(d0v, dgv), sm);
    float e0v = 0.f;
    if (t < NN) {
        e0v = expf(d0v - m);
        e0s[t] = e0v;
        eds[t] = expf(dgv - m);
    }
    const float S = block_sum(e0v, sm);

    const float* Yb = Y + (size_t)b * NN * FEAT + cc + c;
    const int j0 = 32 * qq;
    float p = 0.f;
    for (int jj = 0; jj < 32; jj += 8) {
        float w[8];
        #pragma unroll
        for (int j = 0; j < 8; j++) w[j] = Yb[(size_t)(j0 + jj + j) * FEAT];
        #pragma unroll
        for (int j = 0; j < 8; j++) p = fmaf(e0s[j0 + jj + j], w[j], p);
    }
    bp[qq * 96 + c] = p;
    __syncthreads();
    if (qq == 0) baseY[c] = bp[c] + bp[96 + c] + bp[192 + c] + bp[288 + c];
    __syncthreads();

    const float bY = baseY[c];
    const float vb = ldg<F32>(V_b, cc + c);
    for (int rr = 0; rr < 32; rr += 8) {
        float w[8];
        #pragma unroll
        for (int j = 0; j < 8; j++) w[j] = Yb[(size_t)(j0 + rr + j) * FEAT];
        #pragma unroll
        for (int j = 0; j < 8; j++) {
            const int r = j0 + rr + j;
            const float inv = 1.0f / (S - e0s[r] + eds[r]);
            const float val = (bY + (eds[r] - e0s[r]) * w[j]) * inv + vb;
            stg<F32>(out, (size_t)(b * NN + r) * FEAT + cc + c, val);
        }
    }
}

__global__ __launch_bounds__(384) void k_combine(
    const void* ln_w,
    const float* d0, const float* diag, const float* Y,
    const void* V_b, void* out)
{
    if (is_f32(ln_w))
        combine_body<true >(d0, diag, Y, V_b, out);
    else
        combine_body<false>(d0, diag, Y, V_b, out);
}

extern "C" void kernel_launch(void* const* d_in, const int* in_sizes, int n_in,
                              void* d_out, int out_size, void* d_ws, size_t ws_size,
                              hipStream_t stream) {
    const void* x     = d_in[0];
    const void* U_w   = d_in[1];
    const void* U_b   = d_in[2];
    const void* ln_w  = d_in[3];
    const void* ln_b  = d_in[4];
    const void* enc_w = d_in[5];
    const void* enc_b = d_in[6];
    const void* dec_w = d_in[7];
    const void* dec_b = d_in[8];
    const void* V_w   = d_in[9];
    const void* V_b   = d_in[10];

    float* ws   = (float*)d_ws;
    float* Y    = ws;                     // 512*384  (xh @ V_w, no bias)
    float* d0   = Y + (size_t)BN * FEAT;  // 512
    float* diag = d0 + BN;                // 512

    k_main<<<2 * (BN / 4), 384, 0, stream>>>(x, U_w, U_b, ln_w, ln_b, enc_w, enc_b,
                                             dec_w, dec_b, V_w, Y, d0, diag);
    k_combine<<<4 * BB, 384, 0, stream>>>(ln_w, d0, diag, Y, V_b, d_out);
}

// Round 13
// 102.795 us; speedup vs baseline: 1.1521x; 1.0099x over previous
//
#include <hip/hip_runtime.h>
#include <hip/hip_bf16.h>
#include <math.h>

#define FEAT 384
#define FFN  768
#define ZDIM 384
#define HID  192
#define BB   4
#define NN   128
#define BN   (BB*NN)   // 512 rows

__device__ __forceinline__ float gelu_exact(float x) {
    return 0.5f * x * (1.0f + erff(x * 0.70710678118654752440f));
}

__device__ __forceinline__ float bflo(unsigned u) { return __uint_as_float(u << 16); }
__device__ __forceinline__ float bfhi(unsigned u) { return __uint_as_float(u & 0xFFFF0000u); }

template<bool F32>
__device__ __forceinline__ float ldg(const void* p, int i) {
    if constexpr (F32) return ((const float*)p)[i];
    return __uint_as_float(((unsigned)((const unsigned short*)p)[i]) << 16);
}
template<bool F32>
__device__ __forceinline__ void stg(void* p, size_t i, float v) {
    if constexpr (F32) ((float*)p)[i] = v;
    else ((__hip_bfloat16*)p)[i] = __float2bfloat16(v);
}

// 4-element weight vector: 16B load (fp32) / 8B load (bf16)
template<bool F32> struct V4;
template<> struct V4<true> {
    float4 a;
    __device__ __forceinline__ void load(const void* p, size_t off) {
        a = *(const float4*)((const float*)p + off);
    }
    __device__ __forceinline__ float g(int i) const { return (&a.x)[i]; }
};
template<> struct V4<false> {
    uint2 u;
    __device__ __forceinline__ void load(const void* p, size_t off) {
        u = *(const uint2*)((const unsigned short*)p + off);
    }
    __device__ __forceinline__ float g(int i) const {
        const unsigned w = (&u.x)[i >> 1];
        return (i & 1) ? bfhi(w) : bflo(w);
    }
};

__device__ __forceinline__ bool is_f32(const void* ln_w) {
    return ((const unsigned short*)ln_w)[0] == 0;
}

// ---- block reductions over 384 threads (6 wave64) ----
__device__ __forceinline__ float block_sum(float v, float* sm) {
    for (int o = 32; o > 0; o >>= 1) v += __shfl_down(v, o, 64);
    const int lane = threadIdx.x & 63, w = threadIdx.x >> 6;
    __syncthreads();
    if (lane == 0) sm[w] = v;
    __syncthreads();
    return sm[0] + sm[1] + sm[2] + sm[3] + sm[4] + sm[5];
}
__device__ __forceinline__ float block_max(float v, float* sm) {
    for (int o = 32; o > 0; o >>= 1) v = fmaxf(v, __shfl_down(v, o, 64));
    const int lane = threadIdx.x & 63, w = threadIdx.x >> 6;
    __syncthreads();
    if (lane == 0) sm[w] = v;
    __syncthreads();
    return fmaxf(fmaxf(fmaxf(sm[0], sm[1]), fmaxf(sm[2], sm[3])), fmaxf(sm[4], sm[5]));
}
// 4-wide block sum; sm must hold 24 floats
__device__ __forceinline__ void block_sum4(float v0, float v1, float v2, float v3,
                                           float* sm, float out[4]) {
    for (int o = 32; o > 0; o >>= 1) {
        v0 += __shfl_down(v0, o, 64);
        v1 += __shfl_down(v1, o, 64);
        v2 += __shfl_down(v2, o, 64);
        v3 += __shfl_down(v3, o, 64);
    }
    const int lane = threadIdx.x & 63, w = threadIdx.x >> 6;
    __syncthreads();
    if (lane == 0) { sm[w] = v0; sm[6 + w] = v1; sm[12 + w] = v2; sm[18 + w] = v3; }
    __syncthreads();
    #pragma unroll
    for (int q = 0; q < 4; q++)
        out[q] = sm[q*6] + sm[q*6+1] + sm[q*6+2] + sm[q*6+3] + sm[q*6+4] + sm[q*6+5];
}

// Shared pool (floats): xs 0 (1536), zs 1536 (1536), hid 3072 (768),
// gh 3840 (192)  [gh contiguous after hid => 5th GEMM row], part 4032 (5760),
// sm 9792 (24). Total 9816 = 39.3 KB.
#define SM_TOTAL 9816

// Generic GEMM helper, 3-deep rotating weight staging (24 loads in flight):
// M rows from LDS (in[m*ldin + k]), 4 cols/thread, K-chunk KCH at base kb.
template<bool F32, int KCH, int M>
__device__ __forceinline__ void gemmMx4(
    const void* __restrict__ W, int ldw, int c0, int kb,
    const float* __restrict__ in, int ldin, float acc[M][4])
{
    constexpr int NB = KCH / 8;
    V4<F32> buf[3][8];
    #pragma unroll
    for (int j = 0; j < 8; j++) buf[0][j].load(W, (size_t)(kb + j) * ldw + c0);
    if (NB > 1) {
        #pragma unroll
        for (int j = 0; j < 8; j++) buf[1][j].load(W, (size_t)(kb + 8 + j) * ldw + c0);
    }
    #pragma unroll
    for (int b = 0; b < NB; b++) {
        const int cur = b % 3;
        if (b + 2 < NB) {
            const int nxt = (b + 2) % 3;
            #pragma unroll
            for (int j = 0; j < 8; j++)
                buf[nxt][j].load(W, (size_t)(kb + (b + 2) * 8 + j) * ldw + c0);
        }
        #pragma unroll
        for (int j = 0; j < 8; j++) {
            #pragma unroll
            for (int m = 0; m < M; m++) {
                const float xv = in[m * ldin + kb + b * 8 + j];
                #pragma unroll
                for (int i = 0; i < 4; i++)
                    acc[m][i] = fmaf(xv, buf[cur][j].g(i), acc[m][i]);
            }
        }
    }
}

// ============ Type A: quad q — U z-half -> LN -> enc -> dec -> dots ============
template<bool F32>
__device__ void bodyA(float* S, int q,
    const void* __restrict__ x, const void* __restrict__ U_w,
    const void* __restrict__ U_b, const void* __restrict__ ln_w,
    const void* __restrict__ ln_b, const void* __restrict__ enc_w,
    const void* __restrict__ enc_b, const void* __restrict__ dec_w,
    const void* __restrict__ dec_b,
    float* __restrict__ d0, float* __restrict__ diag)
{
    const int rb = 4 * q;
    const int t = threadIdx.x;
    float* xs = S;          // 4 x 384
    float* zs = S + 1536;   // 4 x 384
    float* hid = S + 3072;  // 4 x 192  (+ gh right after = 5th row)
    float* gh = S + 3840;   // 192
    float* part = S + 4032; // up to 5760
    float* sm = S + 9792;   // 24

    #pragma unroll
    for (int m = 0; m < 4; m++) xs[m * 384 + t] = ldg<F32>(x, (rb + m) * FEAT + t);
    if (t < HID) gh[t] = gelu_exact(ldg<F32>(enc_b, t));
    __syncthreads();

    // ---- U z-half: cg=t%96 -> 4 cols (global 384+4cg); kh=t/96 -> K 96kh..+96 ----
    const int cg = t % 96, kh = t / 96;
    const int cL = 4 * cg, cG = ZDIM + cL, kb = 96 * kh;
    float acc[4][4] = {};
    gemmMx4<F32, 96, 4>(U_w, FFN, cG, kb, xs, 384, acc);
    if (kh > 0) {
        float* p = &part[(kh - 1) * 1536 + cg];
        #pragma unroll
        for (int m = 0; m < 4; m++)
            #pragma unroll
            for (int i = 0; i < 4; i++) p[(m * 4 + i) * 96] = acc[m][i];
    }
    __syncthreads();

    float hv[4][4];
    float s1[4] = {0,0,0,0}, s2[4] = {0,0,0,0};
    if (kh == 0) {
        #pragma unroll
        for (int i = 0; i < 4; i++) {
            const float ub = ldg<F32>(U_b, cG + i);
            #pragma unroll
            for (int m = 0; m < 4; m++) {
                float v = acc[m][i] + ub
                        + part[(m * 4 + i) * 96 + cg]
                        + part[1536 + (m * 4 + i) * 96 + cg]
                        + part[3072 + (m * 4 + i) * 96 + cg];
                v = gelu_exact(v);
                hv[m][i] = v;
                s1[m] += v; s2[m] += v * v;
            }
        }
    }
    float S1[4], S2[4];
    block_sum4(s1[0], s1[1], s1[2], s1[3], sm, S1);
    block_sum4(s2[0], s2[1], s2[2], s2[3], sm, S2);
    if (kh == 0) {
        #pragma unroll
        for (int m = 0; m < 4; m++) {
            const float mu = S1[m] * (1.0f / ZDIM);
            const float rs = rsqrtf(S2[m] * (1.0f / ZDIM) - mu * mu + 1e-5f);
            #pragma unroll
            for (int i = 0; i < 4; i++) {
                const int zc = cL + i;
                zs[m * 384 + zc] = (hv[m][i] - mu) * rs * ldg<F32>(ln_w, zc) + ldg<F32>(ln_b, zc);
            }
        }
    }
    __syncthreads();

    // ---- encoder: cgE=t%48 -> 4 cols of 192; khE=t/48 -> K 48khE..+48 ----
    {
        const int cgE = t % 48, khE = t / 48;
        const int cE = 4 * cgE, kbE = 48 * khE;
        float ea[4][4] = {};
        gemmMx4<F32, 48, 4>(enc_w, HID, cE, kbE, zs, 384, ea);
        if (khE > 0) {
            float* p = &part[(khE - 1) * 768 + cgE];
            #pragma unroll
            for (int m = 0; m < 4; m++)
                #pragma unroll
                for (int i = 0; i < 4; i++) p[(m * 4 + i) * 48] = ea[m][i];
        }
        __syncthreads();
        if (khE == 0) {
            #pragma unroll
            for (int i = 0; i < 4; i++) {
                const float ebv = ldg<F32>(enc_b, cE + i);
                #pragma unroll
                for (int m = 0; m < 4; m++) {
                    float v = ea[m][i] + ebv;
                    #pragma unroll
                    for (int kk = 0; kk < 7; kk++)
                        v += part[kk * 768 + (m * 4 + i) * 48 + cgE];
                    hid[m * 192 + cE + i] = gelu_exact(v);
                }
            }
        }
        __syncthreads();
    }

    // ---- decoder: 5-row GEMM (4 hid rows + gh as row 4) ----
    {
        const int cgD = t % 96, khD = t / 96;
        const int cD = 4 * cgD, kbD = 48 * khD;
        float da[5][4] = {};
        gemmMx4<F32, 48, 5>(dec_w, ZDIM, cD, kbD, hid, 192, da);
        if (khD > 0) {
            float* p = &part[(khD - 1) * 1920 + cgD];
            #pragma unroll
            for (int m = 0; m < 5; m++)
                #pragma unroll
                for (int i = 0; i < 4; i++) p[(m * 4 + i) * 96] = da[m][i];
        }
        __syncthreads();
        float pd[4] = {0,0,0,0}, pe[4] = {0,0,0,0};
        if (khD == 0) {
            #pragma unroll
            for (int i = 0; i < 4; i++) {
                const int c = cD + i;
                const float dbv = ldg<F32>(dec_b, c);
                float vc = da[4][i] + dbv;
                #pragma unroll
                for (int kk = 0; kk < 3; kk++)
                    vc += part[kk * 1920 + (16 + i) * 96 + cgD];
                #pragma unroll
                for (int m = 0; m < 4; m++) {
                    float v = da[m][i] + dbv;
                    #pragma unroll
                    for (int kk = 0; kk < 3; kk++)
                        v += part[kk * 1920 + (m * 4 + i) * 96 + cgD];
                    const float zv = zs[m * 384 + c];
                    pd[m] = fmaf(v, zv, pd[m]);
                    pe[m] = fmaf(vc, zv, pe[m]);
                }
            }
        }
        float DG[4], DD[4];
        block_sum4(pd[0], pd[1], pd[2], pd[3], sm, DG);
        block_sum4(pe[0], pe[1], pe[2], pe[3], sm, DD);
        if (t == 0) {
            #pragma unroll
            for (int m = 0; m < 4; m++) { diag[rb + m] = DG[m]; d0[rb + m] = DD[m]; }
        }
    }
}

// ============ Type B: quad q — U xh-half -> Y = xh @ V_w ============
template<bool F32>
__device__ void bodyB(float* S, int q,
    const void* __restrict__ x, const void* __restrict__ U_w,
    const void* __restrict__ U_b, const void* __restrict__ V_w,
    float* __restrict__ Y)
{
    const int rb = 4 * q;
    const int t = threadIdx.x;
    float* xs = S;          // 4 x 384
    float* zs = S + 1536;   // 4 x 384 (xh)
    float* part = S + 4032;

    #pragma unroll
    for (int m = 0; m < 4; m++) xs[m * 384 + t] = ldg<F32>(x, (rb + m) * FEAT + t);
    __syncthreads();

    const int cg = t % 96, kh = t / 96;
    const int cL = 4 * cg, kb = 96 * kh;
    float acc[4][4] = {};
    gemmMx4<F32, 96, 4>(U_w, FFN, cL, kb, xs, 384, acc);
    if (kh > 0) {
        float* p = &part[(kh - 1) * 1536 + cg];
        #pragma unroll
        for (int m = 0; m < 4; m++)
            #pragma unroll
            for (int i = 0; i < 4; i++) p[(m * 4 + i) * 96] = acc[m][i];
    }
    __syncthreads();
    if (kh == 0) {
        #pragma unroll
        for (int i = 0; i < 4; i++) {
            const float ub = ldg<F32>(U_b, cL + i);
            #pragma unroll
            for (int m = 0; m < 4; m++) {
                float v = acc[m][i] + ub
                        + part[(m * 4 + i) * 96 + cg]
                        + part[1536 + (m * 4 + i) * 96 + cg]
                        + part[3072 + (m * 4 + i) * 96 + cg];
                zs[m * 384 + cL + i] = gelu_exact(v);
            }
        }
    }
    __syncthreads();

    // V: same thread mapping; K = 384 full
    float ya[4][4] = {};
    gemmMx4<F32, 96, 4>(V_w, FEAT, cL, kb, zs, 384, ya);
    if (kh > 0) {
        float* p = &part[(kh - 1) * 1536 + cg];
        #pragma unroll
        for (int m = 0; m < 4; m++)
            #pragma unroll
            for (int i = 0; i < 4; i++) p[(m * 4 + i) * 96] = ya[m][i];
    }
    __syncthreads();
    if (kh == 0) {
        #pragma unroll
        for (int m = 0; m < 4; m++) {
            float o[4];
            #pragma unroll
            for (int i = 0; i < 4; i++) {
                o[i] = ya[m][i]
                     + part[(m * 4 + i) * 96 + cg]
                     + part[1536 + (m * 4 + i) * 96 + cg]
                     + part[3072 + (m * 4 + i) * 96 + cg];
            }
            *(float4*)(Y + (size_t)(rb + m) * FEAT + cL) = make_float4(o[0], o[1], o[2], o[3]);
        }
    }
}

__global__ __launch_bounds__(384) void k_main(
    const void* x, const void* U_w, const void* U_b,
    const void* ln_w, const void* ln_b,
    const void* enc_w, const void* enc_b,
    const void* dec_w, const void* dec_b, const void* V_w,
    float* Y, float* d0, float* diag)
{
    __shared__ float S[SM_TOTAL];   // single pool for all template paths
    const int type = blockIdx.x & 1;
    const int q = blockIdx.x >> 1;
    if (is_f32(ln_w)) {
        if (type == 0) bodyA<true >(S, q, x, U_w, U_b, ln_w, ln_b, enc_w, enc_b, dec_w, dec_b, d0, diag);
        else           bodyB<true >(S, q, x, U_w, U_b, V_w, Y);
    } else {
        if (type == 0) bodyA<false>(S, q, x, U_w, U_b, ln_w, ln_b, enc_w, enc_b, dec_w, dec_b, d0, diag);
        else           bodyB<false>(S, q, x, U_w, U_b, V_w, Y);
    }
}

// ============ K2: 16 blocks = 4 batches x 4 col-chunks of 96 ============
// out_i = (baseY + (ed_i - e0_i) * Y_i) / (S - e0_i + ed_i) + V_b
template<bool F32>
__device__ void combine_body(
    const float* __restrict__ d0, const float* __restrict__ diag,
    const float* __restrict__ Y,
    const void* __restrict__ V_b, void* __restrict__ out)
{
    const int b  = blockIdx.x >> 2;
    const int cc = (blockIdx.x & 3) * 96;
    const int t = threadIdx.x;
    const int c = t % 96, qq = t / 96;
    __shared__ float e0s[NN], eds[NN];
    __shared__ float bp[4 * 96];
    __shared__ float baseY[96];
    __shared__ float sm[12];

    float d0v = -INFINITY, dgv = -INFINITY;
    if (t < NN) { d0v = d0[b * NN + t]; dgv = diag[b * NN + t]; }
    const float m = block_max(fmaxf(d0v, dgv), sm);
    float e0v = 0.f;
    if (t < NN) {
        e0v = expf(d0v - m);
        e0s[t] = e0v;
        eds[t] = expf(dgv - m);
    }
    const float S = block_sum(e0v, sm);

    const float* Yb = Y + (size_t)b * NN * FEAT + cc + c;
    const int j0 = 32 * qq;
    float p = 0.f;
    for (int jj = 0; jj < 32; jj += 8) {
        float w[8];
        #pragma unroll
        for (int j = 0; j < 8; j++) w[j] = Yb[(size_t)(j0 + jj + j) * FEAT];
        #pragma unroll
        for (int j = 0; j < 8; j++) p = fmaf(e0s[j0 + jj + j], w[j], p);
    }
    bp[qq * 96 + c] = p;
    __syncthreads();
    if (qq == 0) baseY[c] = bp[c] + bp[96 + c] + bp[192 + c] + bp[288 + c];
    __syncthreads();

    const float bY = baseY[c];
    const float vb = ldg<F32>(V_b, cc + c);
    for (int rr = 0; rr < 32; rr += 8) {
        float w[8];
        #pragma unroll
        for (int j = 0; j < 8; j++) w[j] = Yb[(size_t)(j0 + rr + j) * FEAT];
        #pragma unroll
        for (int j = 0; j < 8; j++) {
            const int r = j0 + rr + j;
            const float inv = 1.0f / (S - e0s[r] + eds[r]);
            const float val = (bY + (eds[r] - e0s[r]) * w[j]) * inv + vb;
            stg<F32>(out, (size_t)(b * NN + r) * FEAT + cc + c, val);
        }
    }
}

__global__ __launch_bounds__(384) void k_combine(
    const void* ln_w,
    const float* d0, const float* diag, const float* Y,
    const void* V_b, void* out)
{
    if (is_f32(ln_w))
        combine_body<true >(d0, diag, Y, V_b, out);
    else
        combine_body<false>(d0, diag, Y, V_b, out);
}

extern "C" void kernel_launch(void* const* d_in, const int* in_sizes, int n_in,
                              void* d_out, int out_size, void* d_ws, size_t ws_size,
                              hipStream_t stream) {
    const void* x     = d_in[0];
    const void* U_w   = d_in[1];
    const void* U_b   = d_in[2];
    const void* ln_w  = d_in[3];
    const void* ln_b  = d_in[4];
    const void* enc_w = d_in[5];
    const void* enc_b = d_in[6];
    const void* dec_w = d_in[7];
    const void* dec_b = d_in[8];
    const void* V_w   = d_in[9];
    const void* V_b   = d_in[10];

    float* ws   = (float*)d_ws;
    float* Y    = ws;                     // 512*384  (xh @ V_w, no bias)
    float* d0   = Y + (size_t)BN * FEAT;  // 512
    float* diag = d0 + BN;                // 512

    k_main<<<2 * (BN / 4), 384, 0, stream>>>(x, U_w, U_b, ln_w, ln_b, enc_w, enc_b,
                                             dec_w, dec_b, V_w, Y, d0, diag);
    k_combine<<<4 * BB, 384, 0, stream>>>(ln_w, d0, diag, Y, V_b, d_out);
}